// Round 1
// baseline (330.394 us; speedup 1.0000x reference)
//
#include <hip/hip_runtime.h>
#include <math.h>

#define BB 8
#define NN 4096
#define MM 2048
#define CC 256
#define CBD 128

typedef __attribute__((ext_vector_type(8))) short s16x8;
typedef __attribute__((ext_vector_type(4))) float f32x4;
typedef unsigned short u16;
typedef unsigned int u32;

__device__ __forceinline__ u16 f2bf(float f) {
    union { float f; u32 u; } v; v.f = f;
    u32 r = v.u + 0x7fffu + ((v.u >> 16) & 1u);
    return (u16)(r >> 16);
}
__device__ __forceinline__ float bf2f(u16 h) {
    union { u32 u; float f; } v; v.u = ((u32)h) << 16; return v.f;
}

#define MFMA(a, b, c) __builtin_amdgcn_mfma_f32_16x16x32_bf16(a, b, c, 0, 0, 0)

// ---------------------------------------------------------------- split x
__global__ __launch_bounds__(256) void k_split_x(const float* __restrict__ x,
                                                 u16* __restrict__ xh,
                                                 u16* __restrict__ xl, int n4) {
    int i = blockIdx.x * 256 + threadIdx.x;
    if (i >= n4) return;
    float4 v = ((const float4*)x)[i];
    ushort4 h, l;
    h.x = f2bf(v.x); l.x = f2bf(v.x - bf2f(h.x));
    h.y = f2bf(v.y); l.y = f2bf(v.y - bf2f(h.y));
    h.z = f2bf(v.z); l.z = f2bf(v.z - bf2f(h.z));
    h.w = f2bf(v.w); l.w = f2bf(v.w - bf2f(h.w));
    ((ushort4*)xh)[i] = h;
    ((ushort4*)xl)[i] = l;
}

// --------------------------------------------- split + transpose weights
// W_theta/W_phi/W_g: [256][128] -> hi/lo bf16 transposed [128][256]
// W_out:             [128][256] -> bf16 transposed      [256][128]
__global__ __launch_bounds__(256) void k_split_w(
    const float* __restrict__ wt, const float* __restrict__ wp,
    const float* __restrict__ wg, const float* __restrict__ wo,
    u16* wth, u16* wtl, u16* wph, u16* wpl, u16* wgh, u16* wgl, u16* wot) {
    int e = blockIdx.x * 256 + threadIdx.x;
    int m = blockIdx.y;
    if (m < 3) {
        const float* src = m == 0 ? wt : (m == 1 ? wp : wg);
        u16* oh = m == 0 ? wth : (m == 1 ? wph : wgh);
        u16* ol = m == 0 ? wtl : (m == 1 ? wpl : wgl);
        int r = e >> 7, c = e & 127;          // src [256][128]
        float f = src[e];
        u16 hi = f2bf(f);
        oh[c * 256 + r] = hi;
        ol[c * 256 + r] = f2bf(f - bf2f(hi));
    } else {
        int r = e >> 8, c = e & 255;          // src [128][256]
        wot[c * 128 + r] = f2bf(wo[e]);
    }
}

// ------------------------------------------------------- projection GEMM
// mode 0: theta (no pool, split output), 1: phi (pool, split), 2: g (pool, bf16, transposed)
__global__ __launch_bounds__(256) void k_proj(
    const u16* __restrict__ xh, const u16* __restrict__ xl,
    const u16* __restrict__ wth, const u16* __restrict__ wtl,
    const u16* __restrict__ wph, const u16* __restrict__ wpl,
    const u16* __restrict__ wgh, const u16* __restrict__ wgl,
    u16* __restrict__ th, u16* __restrict__ tl,
    u16* __restrict__ ph, u16* __restrict__ pl, u16* __restrict__ gt) {
    __shared__ u16 sa_h[128][40], sa_l[128][40], sw_h[128][40], sw_l[128][40];
    int tid = threadIdx.x;
    int w = tid >> 6, lane = tid & 63, q = lane >> 4, li = lane & 15;
    int r0 = blockIdx.x * 128;
    int mode = blockIdx.y;
    const u16* wh = mode == 0 ? wth : (mode == 1 ? wph : wgh);
    const u16* wl = mode == 0 ? wtl : (mode == 1 ? wpl : wgl);
    int wr = (w >> 1) * 64, wc = (w & 1) * 64;
    f32x4 acc[4][4];
#pragma unroll
    for (int i = 0; i < 4; i++)
#pragma unroll
        for (int j = 0; j < 4; j++) acc[i][j] = (f32x4)0.f;

    for (int kc = 0; kc < 8; kc++) {
#pragma unroll
        for (int i = 0; i < 2; i++) {
            int ch = tid * 2 + i;                 // 0..511
            int row = ch >> 2, cc = (ch & 3) * 8; // 128 rows x 32 k
            size_t ga = (size_t)(r0 + row) * 256 + kc * 32 + cc;
            *(s16x8*)&sa_h[row][cc] = *(const s16x8*)&xh[ga];
            *(s16x8*)&sa_l[row][cc] = *(const s16x8*)&xl[ga];
            size_t gw = (size_t)row * 256 + kc * 32 + cc;
            *(s16x8*)&sw_h[row][cc] = *(const s16x8*)&wh[gw];
            *(s16x8*)&sw_l[row][cc] = *(const s16x8*)&wl[gw];
        }
        __syncthreads();
#pragma unroll
        for (int i = 0; i < 4; i++) {
            s16x8 ahf = *(const s16x8*)&sa_h[wr + i * 16 + li][q * 8];
            s16x8 alf = *(const s16x8*)&sa_l[wr + i * 16 + li][q * 8];
#pragma unroll
            for (int j = 0; j < 4; j++) {
                s16x8 bhf = *(const s16x8*)&sw_h[wc + j * 16 + li][q * 8];
                s16x8 blf = *(const s16x8*)&sw_l[wc + j * 16 + li][q * 8];
                acc[i][j] = MFMA(ahf, bhf, acc[i][j]);
                acc[i][j] = MFMA(ahf, blf, acc[i][j]);
                acc[i][j] = MFMA(alf, bhf, acc[i][j]);
            }
        }
        __syncthreads();
    }

    if (mode == 0) {
#pragma unroll
        for (int i = 0; i < 4; i++)
#pragma unroll
            for (int j = 0; j < 4; j++)
#pragma unroll
                for (int reg = 0; reg < 4; reg++) {
                    int row = r0 + wr + i * 16 + q * 4 + reg;
                    int col = wc + j * 16 + li;
                    float v = acc[i][j][reg];
                    u16 hi = f2bf(v);
                    th[(size_t)row * 128 + col] = hi;
                    tl[(size_t)row * 128 + col] = f2bf(v - bf2f(hi));
                }
    } else {
#pragma unroll
        for (int i = 0; i < 4; i++)
#pragma unroll
            for (int j = 0; j < 4; j++)
#pragma unroll
                for (int pr = 0; pr < 2; pr++) {
                    float v = fmaxf(acc[i][j][pr * 2], acc[i][j][pr * 2 + 1]);
                    int n = r0 + wr + i * 16 + q * 4 + pr * 2; // even
                    int mrow = n >> 1;                          // global pooled row
                    int col = wc + j * 16 + li;
                    if (mode == 1) {
                        u16 hi = f2bf(v);
                        ph[(size_t)mrow * 128 + col] = hi;
                        pl[(size_t)mrow * 128 + col] = f2bf(v - bf2f(hi));
                    } else {
                        int b = n >> 12;
                        int mi = mrow & 2047;
                        gt[(size_t)b * (128 * 2048) + (size_t)col * 2048 + mi] = f2bf(v);
                    }
                }
    }
}

// ------------------------------------------------------- flash attention
__global__ __launch_bounds__(256) void k_attn(
    const u16* __restrict__ th, const u16* __restrict__ tl,
    const u16* __restrict__ ph, const u16* __restrict__ pl,
    const u16* __restrict__ gt, u16* __restrict__ y) {
    __shared__ u16 skh[64][136], skl[64][136], sg[128][72], sp[4][16][72];
    int tid = threadIdx.x, w = tid >> 6, lane = tid & 63, q = lane >> 4, li = lane & 15;
    int b = blockIdx.y;
    int n0 = blockIdx.x * 64;
    size_t qrow = (size_t)b * 4096 + n0 + w * 16 + li;
    s16x8 Qh[4], Ql[4];
#pragma unroll
    for (int ks = 0; ks < 4; ks++) {
        Qh[ks] = *(const s16x8*)&th[qrow * 128 + ks * 32 + q * 8];
        Ql[ks] = *(const s16x8*)&tl[qrow * 128 + ks * 32 + q * 8];
    }
    float mrow[4], lrow[4];
    f32x4 o[8];
#pragma unroll
    for (int r = 0; r < 4; r++) { mrow[r] = -INFINITY; lrow[r] = 0.f; }
#pragma unroll
    for (int c = 0; c < 8; c++) o[c] = (f32x4)0.f;

    for (int kt = 0; kt < 32; kt++) {
        int m0 = kt * 64;
#pragma unroll
        for (int i = 0; i < 4; i++) {
            int ch = tid + i * 256;                  // 0..1023
            int r = ch >> 4, cc = (ch & 15) * 8;     // phi: 64 x 128
            size_t ga = ((size_t)b * 2048 + m0 + r) * 128 + cc;
            *(s16x8*)&skh[r][cc] = *(const s16x8*)&ph[ga];
            *(s16x8*)&skl[r][cc] = *(const s16x8*)&pl[ga];
            int r2 = ch >> 3, c2 = (ch & 7) * 8;     // g: 128 x 64
            *(s16x8*)&sg[r2][c2] =
                *(const s16x8*)&gt[(size_t)b * (128 * 2048) + (size_t)r2 * 2048 + m0 + c2];
        }
        __syncthreads();

        f32x4 s[4];
#pragma unroll
        for (int ct = 0; ct < 4; ct++) s[ct] = (f32x4)0.f;
#pragma unroll
        for (int ks = 0; ks < 4; ks++) {
#pragma unroll
            for (int ct = 0; ct < 4; ct++) {
                s16x8 bh = *(const s16x8*)&skh[ct * 16 + li][ks * 32 + q * 8];
                s16x8 bl = *(const s16x8*)&skl[ct * 16 + li][ks * 32 + q * 8];
                s[ct] = MFMA(Qh[ks], bh, s[ct]);
                s[ct] = MFMA(Qh[ks], bl, s[ct]);
                s[ct] = MFMA(Ql[ks], bh, s[ct]);
            }
        }

#pragma unroll
        for (int reg = 0; reg < 4; reg++) {
            float mx = fmaxf(fmaxf(s[0][reg], s[1][reg]), fmaxf(s[2][reg], s[3][reg]));
#pragma unroll
            for (int off = 1; off < 16; off <<= 1)
                mx = fmaxf(mx, __shfl_xor(mx, off, 64));
            float nm = fmaxf(mrow[reg], mx);
            float al = __expf(mrow[reg] - nm);
            mrow[reg] = nm;
            float p0 = __expf(s[0][reg] - nm);
            float p1 = __expf(s[1][reg] - nm);
            float p2 = __expf(s[2][reg] - nm);
            float p3 = __expf(s[3][reg] - nm);
            float rs = p0 + p1 + p2 + p3;
#pragma unroll
            for (int off = 1; off < 16; off <<= 1)
                rs += __shfl_xor(rs, off, 64);
            lrow[reg] = lrow[reg] * al + rs;
#pragma unroll
            for (int c = 0; c < 8; c++) o[c][reg] *= al;
            sp[w][q * 4 + reg][0 * 16 + li] = f2bf(p0);
            sp[w][q * 4 + reg][1 * 16 + li] = f2bf(p1);
            sp[w][q * 4 + reg][2 * 16 + li] = f2bf(p2);
            sp[w][q * 4 + reg][3 * 16 + li] = f2bf(p3);
        }

#pragma unroll
        for (int ks2 = 0; ks2 < 2; ks2++) {
            s16x8 a = *(const s16x8*)&sp[w][li][ks2 * 32 + q * 8];
#pragma unroll
            for (int c = 0; c < 8; c++) {
                s16x8 bv = *(const s16x8*)&sg[c * 16 + li][ks2 * 32 + q * 8];
                o[c] = MFMA(a, bv, o[c]);
            }
        }
        __syncthreads();
    }

#pragma unroll
    for (int c = 0; c < 8; c++)
#pragma unroll
        for (int reg = 0; reg < 4; reg++) {
            size_t row = (size_t)b * 4096 + n0 + w * 16 + q * 4 + reg;
            y[row * 128 + c * 16 + li] = f2bf(o[c][reg] / lrow[reg]);
        }
}

// --------------------------------------------- output GEMM + residual
__global__ __launch_bounds__(256) void k_out(
    const u16* __restrict__ y, const u16* __restrict__ wot,
    const float* __restrict__ x, float* __restrict__ out) {
    __shared__ u16 sy[128][72], sw[128][72];
    int tid = threadIdx.x, w = tid >> 6, lane = tid & 63, q = lane >> 4, li = lane & 15;
    int r0 = blockIdx.x * 128, c0 = blockIdx.y * 128;
    int wr = (w >> 1) * 64, wc = (w & 1) * 64;
    f32x4 acc[4][4];
#pragma unroll
    for (int i = 0; i < 4; i++)
#pragma unroll
        for (int j = 0; j < 4; j++) acc[i][j] = (f32x4)0.f;

    for (int kc = 0; kc < 2; kc++) {
#pragma unroll
        for (int i = 0; i < 4; i++) {
            int ch = tid + i * 256;
            int r = ch >> 3, cc = (ch & 7) * 8;   // 128 x 64
            *(s16x8*)&sy[r][cc] = *(const s16x8*)&y[(size_t)(r0 + r) * 128 + kc * 64 + cc];
            *(s16x8*)&sw[r][cc] = *(const s16x8*)&wot[(size_t)(c0 + r) * 128 + kc * 64 + cc];
        }
        __syncthreads();
#pragma unroll
        for (int ks = 0; ks < 2; ks++)
#pragma unroll
            for (int i = 0; i < 4; i++) {
                s16x8 a = *(const s16x8*)&sy[wr + i * 16 + li][ks * 32 + q * 8];
#pragma unroll
                for (int j = 0; j < 4; j++) {
                    s16x8 bv = *(const s16x8*)&sw[wc + j * 16 + li][ks * 32 + q * 8];
                    acc[i][j] = MFMA(a, bv, acc[i][j]);
                }
            }
        __syncthreads();
    }
#pragma unroll
    for (int i = 0; i < 4; i++)
#pragma unroll
        for (int j = 0; j < 4; j++)
#pragma unroll
            for (int reg = 0; reg < 4; reg++) {
                size_t row = r0 + wr + i * 16 + q * 4 + reg;
                size_t col = c0 + wc + j * 16 + li;
                out[row * 256 + col] = x[row * 256 + col] + acc[i][j][reg];
            }
}

// ---------------------------------------------------------------- launch
extern "C" void kernel_launch(void* const* d_in, const int* in_sizes, int n_in,
                              void* d_out, int out_size, void* d_ws, size_t ws_size,
                              hipStream_t stream) {
    const float* x  = (const float*)d_in[0];
    const float* wt = (const float*)d_in[1];
    const float* wp = (const float*)d_in[2];
    const float* wg = (const float*)d_in[3];
    const float* wo = (const float*)d_in[4];
    float* out = (float*)d_out;

    char* p = (char*)d_ws;
    auto alloc = [&](size_t bytes) {
        char* r = p;
        p += (bytes + 255) & ~(size_t)255;
        return r;
    };
    const size_t NX = (size_t)BB * NN * CC;       // 8388608
    const size_t NT = (size_t)BB * NN * CBD;      // 4194304
    const size_t NP = (size_t)BB * MM * CBD;      // 2097152

    u16* xh  = (u16*)alloc(NX * 2);
    u16* xl  = (u16*)alloc(NX * 2);
    u16* wth = (u16*)alloc(CC * CBD * 2);
    u16* wtl = (u16*)alloc(CC * CBD * 2);
    u16* wph = (u16*)alloc(CC * CBD * 2);
    u16* wpl = (u16*)alloc(CC * CBD * 2);
    u16* wgh = (u16*)alloc(CC * CBD * 2);
    u16* wgl = (u16*)alloc(CC * CBD * 2);
    u16* wot = (u16*)alloc(CC * CBD * 2);
    u16* th  = (u16*)alloc(NT * 2);
    u16* tl  = (u16*)alloc(NT * 2);
    u16* ph  = (u16*)alloc(NP * 2);
    u16* pl  = (u16*)alloc(NP * 2);
    u16* gt  = (u16*)alloc(NP * 2);
    u16* y   = (u16*)xh;  // alias: xh is dead after k_proj

    k_split_x<<<dim3((NX / 4 + 255) / 256), 256, 0, stream>>>(x, xh, xl, (int)(NX / 4));
    k_split_w<<<dim3(128, 4), 256, 0, stream>>>(wt, wp, wg, wo,
                                                wth, wtl, wph, wpl, wgh, wgl, wot);
    k_proj<<<dim3(256, 3), 256, 0, stream>>>(xh, xl, wth, wtl, wph, wpl, wgh, wgl,
                                             th, tl, ph, pl, gt);
    k_attn<<<dim3(64, 8), 256, 0, stream>>>(th, tl, ph, pl, gt, y);
    k_out<<<dim3(256, 2), 256, 0, stream>>>(y, wot, x, out);
}

// Round 2
// 232.402 us; speedup vs baseline: 1.4217x; 1.4217x over previous
//
#include <hip/hip_runtime.h>
#include <math.h>

#define BB 8
#define NN 4096
#define MM 2048
#define CC 256
#define CBD 128

typedef __attribute__((ext_vector_type(8))) short s16x8;
typedef __attribute__((ext_vector_type(4))) float f32x4;
typedef unsigned short u16;
typedef unsigned int u32;

__device__ __forceinline__ u16 f2bf(float f) {
    union { float f; u32 u; } v; v.f = f;
    u32 r = v.u + 0x7fffu + ((v.u >> 16) & 1u);
    return (u16)(r >> 16);
}
__device__ __forceinline__ float bf2f(u16 h) {
    union { u32 u; float f; } v; v.u = ((u32)h) << 16; return v.f;
}

#define MFMA(a, b, c) __builtin_amdgcn_mfma_f32_16x16x32_bf16(a, b, c, 0, 0, 0)

__device__ __forceinline__ void gload_lds16(const u16* g, u16* l) {
    __builtin_amdgcn_global_load_lds(
        (const __attribute__((address_space(1))) void*)g,
        (__attribute__((address_space(3))) void*)l, 16, 0, 0);
}

// --------------------------------------------- split + transpose weights
__global__ __launch_bounds__(256) void k_split_w(
    const float* __restrict__ wt, const float* __restrict__ wp,
    const float* __restrict__ wg, const float* __restrict__ wo,
    u16* wth, u16* wtl, u16* wph, u16* wpl, u16* wgh, u16* wgl, u16* wot) {
    int e = blockIdx.x * 256 + threadIdx.x;
    int m = blockIdx.y;
    if (m < 3) {
        const float* src = m == 0 ? wt : (m == 1 ? wp : wg);
        u16* oh = m == 0 ? wth : (m == 1 ? wph : wgh);
        u16* ol = m == 0 ? wtl : (m == 1 ? wpl : wgl);
        int r = e >> 7, c = e & 127;          // src [256][128]
        float f = src[e];
        u16 hi = f2bf(f);
        oh[c * 256 + r] = hi;
        ol[c * 256 + r] = f2bf(f - bf2f(hi));
    } else {
        int r = e >> 8, c = e & 255;          // src [128][256]
        wot[c * 128 + r] = f2bf(wo[e]);
    }
}

// --------------------------------- fused split + projection GEMM (2 passes)
// pass 0: theta (3-term, split hi/lo output)
// pass 1: phi (3-term, pool, split) + g (2-term, pool, bf16 transposed)
__global__ __launch_bounds__(256) void k_proj(
    const float* __restrict__ x,
    const u16* __restrict__ wth, const u16* __restrict__ wtl,
    const u16* __restrict__ wph, const u16* __restrict__ wpl,
    const u16* __restrict__ wgh,
    u16* __restrict__ th, u16* __restrict__ tl,
    u16* __restrict__ ph, u16* __restrict__ pl, u16* __restrict__ gt) {
    __shared__ u16 sxh[128][40], sxl[128][40];
    __shared__ u16 sw0[128][40], sw1[128][40], sw2[128][40];
    int tid = threadIdx.x;
    int w = tid >> 6, lane = tid & 63, q = lane >> 4, li = lane & 15;
    int r0 = blockIdx.x * 128;
    int pass = blockIdx.y;
    int wr = (w >> 1) * 64, wc = (w & 1) * 64;
    const u16* WA = pass ? wph : wth;
    const u16* WB = pass ? wpl : wtl;

    f32x4 acc0[4][4], acc1[4][4];
#pragma unroll
    for (int i = 0; i < 4; i++)
#pragma unroll
        for (int j = 0; j < 4; j++) { acc0[i][j] = (f32x4)0.f; acc1[i][j] = (f32x4)0.f; }

    for (int kc = 0; kc < 8; kc++) {
        {   // stage x fp32 -> hi/lo bf16
            int row = tid >> 1, half = tid & 1;
            const float* xp = &x[(size_t)(r0 + row) * 256 + kc * 32 + half * 16];
            float4 v0 = ((const float4*)xp)[0];
            float4 v1 = ((const float4*)xp)[1];
            float4 v2 = ((const float4*)xp)[2];
            float4 v3 = ((const float4*)xp)[3];
            float vv[16] = {v0.x, v0.y, v0.z, v0.w, v1.x, v1.y, v1.z, v1.w,
                            v2.x, v2.y, v2.z, v2.w, v3.x, v3.y, v3.z, v3.w};
            u16 hh[16], ll[16];
#pragma unroll
            for (int t = 0; t < 16; t++) {
                hh[t] = f2bf(vv[t]);
                ll[t] = f2bf(vv[t] - bf2f(hh[t]));
            }
#pragma unroll
            for (int t = 0; t < 2; t++) {
                *(s16x8*)&sxh[row][half * 16 + t * 8] = *(s16x8*)&hh[t * 8];
                *(s16x8*)&sxl[row][half * 16 + t * 8] = *(s16x8*)&ll[t * 8];
            }
        }
#pragma unroll
        for (int i = 0; i < 2; i++) {   // stage W tiles
            int ch = tid * 2 + i;
            int rowc = ch >> 2, cc = (ch & 3) * 8;
            size_t gw = (size_t)rowc * 256 + kc * 32 + cc;
            *(s16x8*)&sw0[rowc][cc] = *(const s16x8*)&WA[gw];
            *(s16x8*)&sw1[rowc][cc] = *(const s16x8*)&WB[gw];
            if (pass) *(s16x8*)&sw2[rowc][cc] = *(const s16x8*)&wgh[gw];
        }
        __syncthreads();
#pragma unroll
        for (int i = 0; i < 4; i++) {
            s16x8 ah = *(const s16x8*)&sxh[wr + i * 16 + li][q * 8];
            s16x8 al = *(const s16x8*)&sxl[wr + i * 16 + li][q * 8];
#pragma unroll
            for (int j = 0; j < 4; j++) {
                s16x8 bh = *(const s16x8*)&sw0[wc + j * 16 + li][q * 8];
                s16x8 bl = *(const s16x8*)&sw1[wc + j * 16 + li][q * 8];
                acc0[i][j] = MFMA(ah, bh, acc0[i][j]);
                acc0[i][j] = MFMA(al, bh, acc0[i][j]);
                acc0[i][j] = MFMA(ah, bl, acc0[i][j]);
                if (pass) {
                    s16x8 bg = *(const s16x8*)&sw2[wc + j * 16 + li][q * 8];
                    acc1[i][j] = MFMA(ah, bg, acc1[i][j]);
                    acc1[i][j] = MFMA(al, bg, acc1[i][j]);
                }
            }
        }
        __syncthreads();
    }

    if (pass == 0) {
#pragma unroll
        for (int i = 0; i < 4; i++)
#pragma unroll
            for (int j = 0; j < 4; j++)
#pragma unroll
                for (int reg = 0; reg < 4; reg++) {
                    int row = r0 + wr + i * 16 + q * 4 + reg;
                    int col = wc + j * 16 + li;
                    float v = acc0[i][j][reg];
                    u16 hi = f2bf(v);
                    th[(size_t)row * 128 + col] = hi;
                    tl[(size_t)row * 128 + col] = f2bf(v - bf2f(hi));
                }
    } else {
#pragma unroll
        for (int i = 0; i < 4; i++)
#pragma unroll
            for (int j = 0; j < 4; j++)
#pragma unroll
                for (int pr = 0; pr < 2; pr++) {
                    int n = r0 + wr + i * 16 + q * 4 + pr * 2;   // even
                    int mrow = n >> 1;
                    int col = wc + j * 16 + li;
                    float vp = fmaxf(acc0[i][j][pr * 2], acc0[i][j][pr * 2 + 1]);
                    u16 hi = f2bf(vp);
                    ph[(size_t)mrow * 128 + col] = hi;
                    pl[(size_t)mrow * 128 + col] = f2bf(vp - bf2f(hi));
                    float vg = fmaxf(acc1[i][j][pr * 2], acc1[i][j][pr * 2 + 1]);
                    int b = n >> 12;
                    int mi = mrow & 2047;
                    gt[(size_t)b * (128 * 2048) + (size_t)col * 2048 + mi] = f2bf(vg);
                }
    }
}

// ------------------------------------------------------- flash attention
// S^T layout (A=phi, B=theta): softmax per-thread over 16 keys + 2 shuffles.
// Swizzled unpadded LDS + global_load_lds(16B) staging.
__global__ __launch_bounds__(256) void k_attn(
    const u16* __restrict__ th, const u16* __restrict__ tl,
    const u16* __restrict__ ph, const u16* __restrict__ pl,
    const u16* __restrict__ gt, u16* __restrict__ y) {
    __shared__ u16 skh[64 * 128];   // keys x d, chunk16 ^= row&7
    __shared__ u16 skl[64 * 128];
    __shared__ u16 sg[128 * 64];    // chan x keys, chunk16 ^= row&7
    __shared__ u16 sp[4 * 16 * 64]; // per-wave P, chunk8 ^= (li&7)<<1
    int tid = threadIdx.x, w = tid >> 6, lane = tid & 63, q = lane >> 4, li = lane & 15;
    int b = blockIdx.y;
    int n0 = blockIdx.x * 64;

    size_t qrow = (size_t)b * 4096 + n0 + w * 16 + li;
    s16x8 Qh[4], Ql[4];
#pragma unroll
    for (int ks = 0; ks < 4; ks++) {
        Qh[ks] = *(const s16x8*)&th[qrow * 128 + ks * 32 + q * 8];
        Ql[ks] = *(const s16x8*)&tl[qrow * 128 + ks * 32 + q * 8];
    }
    float mrow = -INFINITY, lrow = 0.f;
    f32x4 o[8];
#pragma unroll
    for (int c = 0; c < 8; c++) o[c] = (f32x4)0.f;

    int r_hi = lane >> 4, c_hi = lane & 15;    // K staging: 4 rows/load
    int r_lo = lane >> 3, c_lo = lane & 7;     // g staging: 8 rows/load

    for (int kt = 0; kt < 32; kt++) {
        int m0 = kt * 64;
        if (kt) __syncthreads();
#pragma unroll
        for (int jj = 0; jj < 4; jj++) {
            {   // skh / skl: rows w*16+jj*4 .. +3
                int r = w * 16 + jj * 4 + r_hi;
                int gc = c_hi ^ (r & 7);
                size_t ga = (((size_t)(b * 2048 + m0 + r)) << 7) + gc * 8;
                gload_lds16(&ph[ga], &skh[(w * 16 + jj * 4) << 7]);
                gload_lds16(&pl[ga], &skl[(w * 16 + jj * 4) << 7]);
            }
            {   // sg: rows w*32+jj*8 .. +7
                int r = w * 32 + jj * 8 + r_lo;
                int gc = c_lo ^ (r & 7);
                size_t ga = (size_t)b * (128 * 2048) + (size_t)r * 2048 + m0 + gc * 8;
                gload_lds16(&gt[ga], &sg[(w * 32 + jj * 8) << 6]);
            }
        }
        __syncthreads();

        // QK^T (transposed): s[ct][reg] = S[key=ct*16+q*4+reg][query=li]
        f32x4 s[4];
#pragma unroll
        for (int ct = 0; ct < 4; ct++) s[ct] = (f32x4)0.f;
#pragma unroll
        for (int ks = 0; ks < 4; ks++) {
#pragma unroll
            for (int ct = 0; ct < 4; ct++) {
                int off = ((ct * 16 + li) << 7) + (((ks * 4 + q) ^ (li & 7)) << 3);
                s16x8 ah = *(const s16x8*)&skh[off];
                s16x8 al = *(const s16x8*)&skl[off];
                s[ct] = MFMA(ah, Qh[ks], s[ct]);
                s[ct] = MFMA(al, Qh[ks], s[ct]);
                s[ct] = MFMA(ah, Ql[ks], s[ct]);
            }
        }

        // online softmax, per-thread over 16 keys then xor-16/32
        float vmax = s[0][0];
#pragma unroll
        for (int ct = 0; ct < 4; ct++)
#pragma unroll
            for (int r = 0; r < 4; r++) vmax = fmaxf(vmax, s[ct][r]);
        vmax = fmaxf(vmax, __shfl_xor(vmax, 16, 64));
        vmax = fmaxf(vmax, __shfl_xor(vmax, 32, 64));
        float nm = fmaxf(mrow, vmax);
        float alph = __expf(mrow - nm);
        mrow = nm;
        float rs = 0.f;
#pragma unroll
        for (int ct = 0; ct < 4; ct++)
#pragma unroll
            for (int r = 0; r < 4; r++) {
                float p = __expf(s[ct][r] - nm);
                s[ct][r] = p;
                rs += p;
            }
        rs += __shfl_xor(rs, 16, 64);
        rs += __shfl_xor(rs, 32, 64);
        lrow = lrow * alph + rs;
#pragma unroll
        for (int reg = 0; reg < 4; reg++) {
            float a2 = __shfl(alph, q * 4 + reg, 64);
#pragma unroll
            for (int c = 0; c < 8; c++) o[c][reg] *= a2;
        }
        // P -> sp (A-layout), packed b64, 8B-chunk swizzle
#pragma unroll
        for (int ct = 0; ct < 4; ct++) {
            u32 lo = (u32)f2bf(s[ct][0]) | ((u32)f2bf(s[ct][1]) << 16);
            u32 hi = (u32)f2bf(s[ct][2]) | ((u32)f2bf(s[ct][3]) << 16);
            uint2 pk; pk.x = lo; pk.y = hi;
            int off = ((w * 16 + li) << 6) + (((ct * 4 + q) ^ ((li & 7) << 1)) << 2);
            *(uint2*)&sp[off] = pk;
        }
        // P @ V
#pragma unroll
        for (int ks2 = 0; ks2 < 2; ks2++) {
            int aoff = ((w * 16 + li) << 6) + ((((ks2 * 4 + q) << 1) ^ ((li & 7) << 1)) << 2);
            s16x8 a = *(const s16x8*)&sp[aoff];
#pragma unroll
            for (int c = 0; c < 8; c++) {
                int boff = ((c * 16 + li) << 6) + (((ks2 * 4 + q) ^ (li & 7)) << 3);
                s16x8 bv = *(const s16x8*)&sg[boff];
                o[c] = MFMA(a, bv, o[c]);
            }
        }
    }

    float inv[4];
#pragma unroll
    for (int reg = 0; reg < 4; reg++) inv[reg] = 1.f / __shfl(lrow, q * 4 + reg, 64);
#pragma unroll
    for (int c = 0; c < 8; c++)
#pragma unroll
        for (int reg = 0; reg < 4; reg++) {
            size_t row = (size_t)b * 4096 + n0 + w * 16 + q * 4 + reg;
            y[row * 128 + c * 16 + li] = f2bf(o[c][reg] * inv[reg]);
        }
}

// --------------------------------------------- output GEMM + residual
__global__ __launch_bounds__(256) void k_out(
    const u16* __restrict__ y, const u16* __restrict__ wot,
    const float* __restrict__ x, float* __restrict__ out) {
    __shared__ u16 sy[128][72], sw[128][72];
    int tid = threadIdx.x, w = tid >> 6, lane = tid & 63, q = lane >> 4, li = lane & 15;
    int r0 = blockIdx.x * 128, c0 = blockIdx.y * 128;
    int wr = (w >> 1) * 64, wc = (w & 1) * 64;
    f32x4 acc[4][4];
#pragma unroll
    for (int i = 0; i < 4; i++)
#pragma unroll
        for (int j = 0; j < 4; j++) acc[i][j] = (f32x4)0.f;

    for (int kc = 0; kc < 2; kc++) {
#pragma unroll
        for (int i = 0; i < 4; i++) {
            int ch = tid + i * 256;
            int r = ch >> 3, cc = (ch & 7) * 8;
            *(s16x8*)&sy[r][cc] = *(const s16x8*)&y[(size_t)(r0 + r) * 128 + kc * 64 + cc];
            *(s16x8*)&sw[r][cc] = *(const s16x8*)&wot[(size_t)(c0 + r) * 128 + kc * 64 + cc];
        }
        __syncthreads();
#pragma unroll
        for (int ks = 0; ks < 2; ks++)
#pragma unroll
            for (int i = 0; i < 4; i++) {
                s16x8 a = *(const s16x8*)&sy[wr + i * 16 + li][ks * 32 + q * 8];
#pragma unroll
                for (int j = 0; j < 4; j++) {
                    s16x8 bv = *(const s16x8*)&sw[wc + j * 16 + li][ks * 32 + q * 8];
                    acc[i][j] = MFMA(a, bv, acc[i][j]);
                }
            }
        __syncthreads();
    }
#pragma unroll
    for (int i = 0; i < 4; i++)
#pragma unroll
        for (int j = 0; j < 4; j++)
#pragma unroll
            for (int reg = 0; reg < 4; reg++) {
                size_t row = r0 + wr + i * 16 + q * 4 + reg;
                size_t col = c0 + wc + j * 16 + li;
                out[row * 256 + col] = x[row * 256 + col] + acc[i][j][reg];
            }
}

// ---------------------------------------------------------------- launch
extern "C" void kernel_launch(void* const* d_in, const int* in_sizes, int n_in,
                              void* d_out, int out_size, void* d_ws, size_t ws_size,
                              hipStream_t stream) {
    const float* x  = (const float*)d_in[0];
    const float* wt = (const float*)d_in[1];
    const float* wp = (const float*)d_in[2];
    const float* wg = (const float*)d_in[3];
    const float* wo = (const float*)d_in[4];
    float* out = (float*)d_out;

    char* p = (char*)d_ws;
    auto alloc = [&](size_t bytes) {
        char* r = p;
        p += (bytes + 255) & ~(size_t)255;
        return r;
    };
    const size_t NX = (size_t)BB * NN * CC;
    const size_t NT = (size_t)BB * NN * CBD;
    const size_t NP = (size_t)BB * MM * CBD;

    u16* yb  = (u16*)alloc(NT * 2);           // y buffer
    u16* wth = (u16*)alloc(CC * CBD * 2);
    u16* wtl = (u16*)alloc(CC * CBD * 2);
    u16* wph = (u16*)alloc(CC * CBD * 2);
    u16* wpl = (u16*)alloc(CC * CBD * 2);
    u16* wgh = (u16*)alloc(CC * CBD * 2);
    u16* wgl = (u16*)alloc(CC * CBD * 2);
    u16* wot = (u16*)alloc(CC * CBD * 2);
    u16* th  = (u16*)alloc(NT * 2);
    u16* tl  = (u16*)alloc(NT * 2);
    u16* ph  = (u16*)alloc(NP * 2);
    u16* pl  = (u16*)alloc(NP * 2);
    u16* gt  = (u16*)alloc(NP * 2);
    (void)NX;

    k_split_w<<<dim3(128, 4), 256, 0, stream>>>(wt, wp, wg, wo,
                                                wth, wtl, wph, wpl, wgh, wgl, wot);
    k_proj<<<dim3(256, 2), 256, 0, stream>>>(x, wth, wtl, wph, wpl, wgh,
                                             th, tl, ph, pl, gt);
    k_attn<<<dim3(64, 8), 256, 0, stream>>>(th, tl, ph, pl, gt, yb);
    k_out<<<dim3(256, 2), 256, 0, stream>>>(yb, wot, x, out);
}

// Round 3
// 210.601 us; speedup vs baseline: 1.5688x; 1.1035x over previous
//
#include <hip/hip_runtime.h>
#include <math.h>

#define BB 8
#define NN 4096
#define MM 2048
#define CC 256
#define CBD 128

typedef __attribute__((ext_vector_type(8))) short s16x8;
typedef __attribute__((ext_vector_type(4))) float f32x4;
typedef __attribute__((ext_vector_type(16))) float f32x16;
typedef unsigned short u16;
typedef unsigned int u32;

__device__ __forceinline__ u16 f2bf(float f) {
    union { float f; u32 u; } v; v.f = f;
    u32 r = v.u + 0x7fffu + ((v.u >> 16) & 1u);
    return (u16)(r >> 16);
}
__device__ __forceinline__ float bf2f(u16 h) {
    union { u32 u; float f; } v; v.u = ((u32)h) << 16; return v.f;
}

#define MFMA(a, b, c)   __builtin_amdgcn_mfma_f32_16x16x32_bf16(a, b, c, 0, 0, 0)
#define MFMA32(a, b, c) __builtin_amdgcn_mfma_f32_32x32x16_bf16(a, b, c, 0, 0, 0)

__device__ __forceinline__ void gload_lds16(const u16* g, u16* l) {
    __builtin_amdgcn_global_load_lds(
        (const __attribute__((address_space(1))) void*)g,
        (__attribute__((address_space(3))) void*)l, 16, 0, 0);
}

// --------------------------------------------- split + transpose weights
__global__ __launch_bounds__(256) void k_split_w(
    const float* __restrict__ wt, const float* __restrict__ wp,
    const float* __restrict__ wg, const float* __restrict__ wo,
    u16* wth, u16* wtl, u16* wph, u16* wpl, u16* wgh, u16* wgl, u16* wot) {
    int e = blockIdx.x * 256 + threadIdx.x;
    int m = blockIdx.y;
    if (m < 3) {
        const float* src = m == 0 ? wt : (m == 1 ? wp : wg);
        u16* oh = m == 0 ? wth : (m == 1 ? wph : wgh);
        u16* ol = m == 0 ? wtl : (m == 1 ? wpl : wgl);
        int r = e >> 7, c = e & 127;          // src [256][128]
        float f = src[e];
        u16 hi = f2bf(f);
        oh[c * 256 + r] = hi;
        ol[c * 256 + r] = f2bf(f - bf2f(hi));
    } else {
        int r = e >> 8, c = e & 255;          // src [128][256]
        wot[c * 128 + r] = f2bf(wo[e]);
    }
}

// --------------------------------- fused split + projection GEMM (2 passes)
__global__ __launch_bounds__(256) void k_proj(
    const float* __restrict__ x,
    const u16* __restrict__ wth, const u16* __restrict__ wtl,
    const u16* __restrict__ wph, const u16* __restrict__ wpl,
    const u16* __restrict__ wgh,
    u16* __restrict__ th, u16* __restrict__ tl,
    u16* __restrict__ ph, u16* __restrict__ pl, u16* __restrict__ gt) {
    __shared__ u16 sxh[128][40], sxl[128][40];
    __shared__ u16 sw0[128][40], sw1[128][40], sw2[128][40];
    int tid = threadIdx.x;
    int w = tid >> 6, lane = tid & 63, q = lane >> 4, li = lane & 15;
    int r0 = blockIdx.x * 128;
    int pass = blockIdx.y;
    int wr = (w >> 1) * 64, wc = (w & 1) * 64;
    const u16* WA = pass ? wph : wth;
    const u16* WB = pass ? wpl : wtl;

    f32x4 acc0[4][4], acc1[4][4];
#pragma unroll
    for (int i = 0; i < 4; i++)
#pragma unroll
        for (int j = 0; j < 4; j++) { acc0[i][j] = (f32x4)0.f; acc1[i][j] = (f32x4)0.f; }

    for (int kc = 0; kc < 8; kc++) {
        {
            int row = tid >> 1, half = tid & 1;
            const float* xp = &x[(size_t)(r0 + row) * 256 + kc * 32 + half * 16];
            float4 v0 = ((const float4*)xp)[0];
            float4 v1 = ((const float4*)xp)[1];
            float4 v2 = ((const float4*)xp)[2];
            float4 v3 = ((const float4*)xp)[3];
            float vv[16] = {v0.x, v0.y, v0.z, v0.w, v1.x, v1.y, v1.z, v1.w,
                            v2.x, v2.y, v2.z, v2.w, v3.x, v3.y, v3.z, v3.w};
            u16 hh[16], ll[16];
#pragma unroll
            for (int t = 0; t < 16; t++) {
                hh[t] = f2bf(vv[t]);
                ll[t] = f2bf(vv[t] - bf2f(hh[t]));
            }
#pragma unroll
            for (int t = 0; t < 2; t++) {
                *(s16x8*)&sxh[row][half * 16 + t * 8] = *(s16x8*)&hh[t * 8];
                *(s16x8*)&sxl[row][half * 16 + t * 8] = *(s16x8*)&ll[t * 8];
            }
        }
#pragma unroll
        for (int i = 0; i < 2; i++) {
            int ch = tid * 2 + i;
            int rowc = ch >> 2, cc = (ch & 3) * 8;
            size_t gw = (size_t)rowc * 256 + kc * 32 + cc;
            *(s16x8*)&sw0[rowc][cc] = *(const s16x8*)&WA[gw];
            *(s16x8*)&sw1[rowc][cc] = *(const s16x8*)&WB[gw];
            if (pass) *(s16x8*)&sw2[rowc][cc] = *(const s16x8*)&wgh[gw];
        }
        __syncthreads();
#pragma unroll
        for (int i = 0; i < 4; i++) {
            s16x8 ah = *(const s16x8*)&sxh[wr + i * 16 + li][q * 8];
            s16x8 al = *(const s16x8*)&sxl[wr + i * 16 + li][q * 8];
#pragma unroll
            for (int j = 0; j < 4; j++) {
                s16x8 bh = *(const s16x8*)&sw0[wc + j * 16 + li][q * 8];
                s16x8 bl = *(const s16x8*)&sw1[wc + j * 16 + li][q * 8];
                acc0[i][j] = MFMA(ah, bh, acc0[i][j]);
                acc0[i][j] = MFMA(al, bh, acc0[i][j]);
                acc0[i][j] = MFMA(ah, bl, acc0[i][j]);
                if (pass) {
                    s16x8 bg = *(const s16x8*)&sw2[wc + j * 16 + li][q * 8];
                    acc1[i][j] = MFMA(ah, bg, acc1[i][j]);
                    acc1[i][j] = MFMA(al, bg, acc1[i][j]);
                }
            }
        }
        __syncthreads();
    }

    if (pass == 0) {
#pragma unroll
        for (int i = 0; i < 4; i++)
#pragma unroll
            for (int j = 0; j < 4; j++)
#pragma unroll
                for (int reg = 0; reg < 4; reg++) {
                    int row = r0 + wr + i * 16 + q * 4 + reg;
                    int col = wc + j * 16 + li;
                    float v = acc0[i][j][reg];
                    u16 hi = f2bf(v);
                    th[(size_t)row * 128 + col] = hi;
                    tl[(size_t)row * 128 + col] = f2bf(v - bf2f(hi));
                }
    } else {
#pragma unroll
        for (int i = 0; i < 4; i++)
#pragma unroll
            for (int j = 0; j < 4; j++)
#pragma unroll
                for (int pr = 0; pr < 2; pr++) {
                    int n = r0 + wr + i * 16 + q * 4 + pr * 2;
                    int mrow = n >> 1;
                    int col = wc + j * 16 + li;
                    float vp = fmaxf(acc0[i][j][pr * 2], acc0[i][j][pr * 2 + 1]);
                    u16 hi = f2bf(vp);
                    ph[(size_t)mrow * 128 + col] = hi;
                    pl[(size_t)mrow * 128 + col] = f2bf(vp - bf2f(hi));
                    float vg = fmaxf(acc1[i][j][pr * 2], acc1[i][j][pr * 2 + 1]);
                    int b = n >> 12;
                    int mi = mrow & 2047;
                    gt[(size_t)b * (128 * 2048) + (size_t)col * 2048 + mi] = f2bf(vg);
                }
    }
}

// ------------------------------------------------------- flash attention
// 32 queries/wave via 32x32x16 MFMA, split-K x2. Writes unnormalized O
// (bf16, [q][ch] via LDS transpose) + per-query (m,l) for the combine.
__global__ __launch_bounds__(256, 2) void k_attn(
    const u16* __restrict__ th, const u16* __restrict__ tl,
    const u16* __restrict__ ph, const u16* __restrict__ pl,
    const u16* __restrict__ gt, u16* __restrict__ ot,
    float* __restrict__ Mv, float* __restrict__ Lv) {
    __shared__ u16 smem[33792];          // 66 KB
    u16* skh = smem;                     // 64 x 128, chunk16 ^= row&7
    u16* skl = smem + 8192;
    u16* sg  = smem + 16384;             // 128 x 64, chunk16 ^= row&7
    u16* sp  = smem + 24576;             // 4 waves x 32 x 72
    int tid = threadIdx.x, w = tid >> 6, lane = tid & 63;
    int q = lane & 31, b = lane >> 5;
    int bb = blockIdx.y;
    int qt = blockIdx.x >> 1, s = blockIdx.x & 1;
    int n0 = qt * 128;
    int row128 = w * 32 + q;
    size_t qrow = ((size_t)bb * 4096 + n0 + row128) * 128;

    s16x8 Qh[8], Ql[8];
#pragma unroll
    for (int ks = 0; ks < 8; ks++) {
        Qh[ks] = *(const s16x8*)&th[qrow + ks * 16 + b * 8];
        Ql[ks] = *(const s16x8*)&tl[qrow + ks * 16 + b * 8];
    }
    float mrow = -INFINITY, lrow = 0.f;
    f32x16 o[4];
#pragma unroll
    for (int c = 0; c < 4; c++) o[c] = (f32x16)0.f;

    int r_hi = lane >> 4, c_hi = lane & 15;
    int r_lo = lane >> 3, c_lo = lane & 7;
    int k0 = s * 1024;

    for (int kt = 0; kt < 16; kt++) {
        int m0 = k0 + kt * 64;
        if (kt) __syncthreads();
#pragma unroll
        for (int jj = 0; jj < 4; jj++) {
            int r = w * 16 + jj * 4 + r_hi;
            int gc = c_hi ^ (r & 7);
            size_t ga = (((size_t)(bb * 2048 + m0 + r)) << 7) + gc * 8;
            gload_lds16(&ph[ga], &skh[(w * 16 + jj * 4) << 7]);
            gload_lds16(&pl[ga], &skl[(w * 16 + jj * 4) << 7]);
            int r2 = w * 32 + jj * 8 + r_lo;
            int gc2 = c_lo ^ (r2 & 7);
            size_t ga2 = (size_t)bb * (128 * 2048) + (size_t)r2 * 2048 + m0 + gc2 * 8;
            gload_lds16(&gt[ga2], &sg[(w * 32 + jj * 8) << 6]);
        }
        __syncthreads();

        // S^T = phi . theta^T : D[key][query], col=query=lane&31
        f32x16 S0 = (f32x16)0.f, S1 = (f32x16)0.f;
#pragma unroll
        for (int ks = 0; ks < 8; ks++) {
            int off0 = (q << 7) + (((ks * 2 + b) ^ (q & 7)) << 3);
            int r1 = 32 + q;
            int off1 = (r1 << 7) + (((ks * 2 + b) ^ (r1 & 7)) << 3);
            s16x8 ah0 = *(const s16x8*)&skh[off0];
            s16x8 al0 = *(const s16x8*)&skl[off0];
            s16x8 ah1 = *(const s16x8*)&skh[off1];
            s16x8 al1 = *(const s16x8*)&skl[off1];
            S0 = MFMA32(ah0, Qh[ks], S0);
            S1 = MFMA32(ah1, Qh[ks], S1);
            S0 = MFMA32(al0, Qh[ks], S0);
            S1 = MFMA32(al1, Qh[ks], S1);
            S0 = MFMA32(ah0, Ql[ks], S0);
            S1 = MFMA32(ah1, Ql[ks], S1);
        }

        // online softmax: per-thread 32 keys + one xor-32 shuffle
        float vmax = S0[0];
#pragma unroll
        for (int r = 0; r < 16; r++) {
            vmax = fmaxf(vmax, S0[r]);
            vmax = fmaxf(vmax, S1[r]);
        }
        vmax = fmaxf(vmax, __shfl_xor(vmax, 32, 64));
        float nm = fmaxf(mrow, vmax);
        float alph = __expf(mrow - nm);
        mrow = nm;
        float rs = 0.f;
#pragma unroll
        for (int r = 0; r < 16; r++) {
            float p0 = __expf(S0[r] - nm); S0[r] = p0; rs += p0;
            float p1 = __expf(S1[r] - nm); S1[r] = p1; rs += p1;
        }
        rs += __shfl_xor(rs, 32, 64);
        lrow = lrow * alph + rs;
#pragma unroll
        for (int c = 0; c < 4; c++)
#pragma unroll
            for (int r = 0; r < 16; r++) o[c][r] *= alph;

        // P -> sp [query][72 keys-stride], b64 packed
        u16* spw = sp + w * 2304;
#pragma unroll
        for (int p2 = 0; p2 < 4; p2++) {
            uint2 pk0, pk1;
            pk0.x = (u32)f2bf(S0[4 * p2])     | ((u32)f2bf(S0[4 * p2 + 1]) << 16);
            pk0.y = (u32)f2bf(S0[4 * p2 + 2]) | ((u32)f2bf(S0[4 * p2 + 3]) << 16);
            pk1.x = (u32)f2bf(S1[4 * p2])     | ((u32)f2bf(S1[4 * p2 + 1]) << 16);
            pk1.y = (u32)f2bf(S1[4 * p2 + 2]) | ((u32)f2bf(S1[4 * p2 + 3]) << 16);
            *(uint2*)&spw[q * 72 + p2 * 8 + b * 4]      = pk0;
            *(uint2*)&spw[q * 72 + 32 + p2 * 8 + b * 4] = pk1;
        }
        // P @ V : O^T[ch][query]
#pragma unroll
        for (int ks2 = 0; ks2 < 4; ks2++) {
            s16x8 Pf = *(const s16x8*)&spw[q * 72 + ks2 * 16 + b * 8];
#pragma unroll
            for (int c = 0; c < 4; c++) {
                int ch = c * 32 + q;
                int off = (ch << 6) + (((ks2 * 2 + b) ^ (ch & 7)) << 3);
                s16x8 gv = *(const s16x8*)&sg[off];
                o[c] = MFMA32(gv, Pf, o[c]);
            }
        }
    }
    __syncthreads();

    // epilogue: LDS transpose O^T[ch][q] -> [q][ch], store bf16 unnormalized
    u16* sc = smem;  // 128 x 136 u16 = 34816 B (fits in skh+skl+sg region)
#pragma unroll
    for (int c = 0; c < 4; c++)
#pragma unroll
        for (int r2 = 0; r2 < 8; r2++) {
            int ch = c * 32 + ((r2 & 1) << 1) + 8 * (r2 >> 1) + 4 * b;
            u32 pk = (u32)f2bf(o[c][2 * r2]) | ((u32)f2bf(o[c][2 * r2 + 1]) << 16);
            *(u32*)&sc[row128 * 136 + ch] = pk;
        }
    __syncthreads();
    size_t obase = ((size_t)s * 32768 + (size_t)bb * 4096 + n0) * 128;
    int rowy = tid >> 1;
#pragma unroll
    for (int j = 0; j < 8; j++) {
        int chk = (tid & 1) * 8 + j;
        s16x8 v = *(const s16x8*)&sc[rowy * 136 + chk * 8];
        *(s16x8*)&ot[obase + (size_t)rowy * 128 + chk * 8] = v;
    }
    if (b == 0) {
        int gi = s * 32768 + bb * 4096 + n0 + row128;
        Mv[gi] = mrow;
        Lv[gi] = lrow;
    }
}

// ------------------------- output GEMM + residual + split-K combine
__global__ __launch_bounds__(256) void k_out(
    const u16* __restrict__ ot, const float* __restrict__ Mv,
    const float* __restrict__ Lv, const u16* __restrict__ wot,
    const float* __restrict__ x, float* __restrict__ out) {
    __shared__ u16 sy[128][72], sw[128][72];
    int tid = threadIdx.x, w = tid >> 6, lane = tid & 63, q = lane >> 4, li = lane & 15;
    int r0 = blockIdx.x * 128, c0 = blockIdx.y * 128;
    int wr = (w >> 1) * 64, wc = (w & 1) * 64;
    const size_t OS = (size_t)32768 * 128;

    float a1v[4], a2v[4];
#pragma unroll
    for (int i = 0; i < 4; i++) {
        int r = (tid + i * 256) >> 3;
        int gr = r0 + r;
        float m1 = Mv[gr], m2 = Mv[32768 + gr];
        float l1 = Lv[gr], l2 = Lv[32768 + gr];
        float Mx = fmaxf(m1, m2);
        float e1 = __expf(m1 - Mx), e2 = __expf(m2 - Mx);
        float Lt = l1 * e1 + l2 * e2;
        a1v[i] = e1 / Lt;
        a2v[i] = e2 / Lt;
    }

    f32x4 acc[4][4];
#pragma unroll
    for (int i = 0; i < 4; i++)
#pragma unroll
        for (int j = 0; j < 4; j++) acc[i][j] = (f32x4)0.f;

    for (int kc = 0; kc < 2; kc++) {
#pragma unroll
        for (int i = 0; i < 4; i++) {
            int ch = tid + i * 256;
            int r = ch >> 3, cc = (ch & 7) * 8;
            size_t ga = (size_t)(r0 + r) * 128 + kc * 64 + cc;
            s16x8 o1 = *(const s16x8*)&ot[ga];
            s16x8 o2 = *(const s16x8*)&ot[OS + ga];
            s16x8 yv;
#pragma unroll
            for (int e = 0; e < 8; e++)
                yv[e] = (short)f2bf(bf2f((u16)o1[e]) * a1v[i] +
                                    bf2f((u16)o2[e]) * a2v[i]);
            *(s16x8*)&sy[r][cc] = yv;
            *(s16x8*)&sw[r][cc] = *(const s16x8*)&wot[(size_t)(c0 + r) * 128 + kc * 64 + cc];
        }
        __syncthreads();
#pragma unroll
        for (int ks = 0; ks < 2; ks++)
#pragma unroll
            for (int i = 0; i < 4; i++) {
                s16x8 a = *(const s16x8*)&sy[wr + i * 16 + li][ks * 32 + q * 8];
#pragma unroll
                for (int j = 0; j < 4; j++) {
                    s16x8 bv = *(const s16x8*)&sw[wc + j * 16 + li][ks * 32 + q * 8];
                    acc[i][j] = MFMA(a, bv, acc[i][j]);
                }
            }
        __syncthreads();
    }
#pragma unroll
    for (int i = 0; i < 4; i++)
#pragma unroll
        for (int j = 0; j < 4; j++)
#pragma unroll
            for (int reg = 0; reg < 4; reg++) {
                size_t row = r0 + wr + i * 16 + q * 4 + reg;
                size_t col = c0 + wc + j * 16 + li;
                out[row * 256 + col] = x[row * 256 + col] + acc[i][j][reg];
            }
}

// ---------------------------------------------------------------- launch
extern "C" void kernel_launch(void* const* d_in, const int* in_sizes, int n_in,
                              void* d_out, int out_size, void* d_ws, size_t ws_size,
                              hipStream_t stream) {
    const float* x  = (const float*)d_in[0];
    const float* wt = (const float*)d_in[1];
    const float* wp = (const float*)d_in[2];
    const float* wg = (const float*)d_in[3];
    const float* wo = (const float*)d_in[4];
    float* out = (float*)d_out;

    char* p = (char*)d_ws;
    auto alloc = [&](size_t bytes) {
        char* r = p;
        p += (bytes + 255) & ~(size_t)255;
        return r;
    };
    const size_t NT = (size_t)BB * NN * CBD;   // 4194304
    const size_t NP = (size_t)BB * MM * CBD;   // 2097152

    u16* wth = (u16*)alloc(CC * CBD * 2);
    u16* wtl = (u16*)alloc(CC * CBD * 2);
    u16* wph = (u16*)alloc(CC * CBD * 2);
    u16* wpl = (u16*)alloc(CC * CBD * 2);
    u16* wgh = (u16*)alloc(CC * CBD * 2);
    u16* wgl = (u16*)alloc(CC * CBD * 2);
    u16* wot = (u16*)alloc(CC * CBD * 2);
    u16* th  = (u16*)alloc(NT * 2);
    u16* tl  = (u16*)alloc(NT * 2);
    u16* ph  = (u16*)alloc(NP * 2);
    u16* pl  = (u16*)alloc(NP * 2);
    u16* gt  = (u16*)alloc(NP * 2);
    u16* ot  = (u16*)alloc(2 * NT * 2);        // [2][32768][128] bf16
    float* Mv = (float*)alloc(2 * 32768 * 4);
    float* Lv = (float*)alloc(2 * 32768 * 4);

    k_split_w<<<dim3(128, 4), 256, 0, stream>>>(wt, wp, wg, wo,
                                                wth, wtl, wph, wpl, wgh, wgl, wot);
    k_proj<<<dim3(256, 2), 256, 0, stream>>>(x, wth, wtl, wph, wpl, wgh,
                                             th, tl, ph, pl, gt);
    k_attn<<<dim3(64, 8), 256, 0, stream>>>(th, tl, ph, pl, gt, ot, Mv, Lv);
    k_out<<<dim3(256, 2), 256, 0, stream>>>(ot, Mv, Lv, wot, x, out);
}

// Round 5
// 202.285 us; speedup vs baseline: 1.6333x; 1.0411x over previous
//
#include <hip/hip_runtime.h>
#include <math.h>

#define BB 8
#define NN 4096
#define MM 2048
#define CC 256
#define CBD 128

typedef __attribute__((ext_vector_type(8))) short s16x8;
typedef __attribute__((ext_vector_type(4))) float f32x4;
typedef __attribute__((ext_vector_type(16))) float f32x16;
typedef unsigned short u16;
typedef unsigned int u32;

__device__ __forceinline__ u16 f2bf(float f) {
    union { float f; u32 u; } v; v.f = f;
    u32 r = v.u + 0x7fffu + ((v.u >> 16) & 1u);
    return (u16)(r >> 16);
}
__device__ __forceinline__ float bf2f(u16 h) {
    union { u32 u; float f; } v; v.u = ((u32)h) << 16; return v.f;
}
__device__ __forceinline__ u32 asu(float f) {
    union { float f; u32 u; } v; v.f = f; return v.u;
}
// pack two f32 -> packed bf16 (truncate): low16 = lo, high16 = hi
__device__ __forceinline__ u32 pkbf(float lo, float hi) {
    return __builtin_amdgcn_perm(asu(hi), asu(lo), 0x07060302u);
}

#define MFMA(a, b, c)   __builtin_amdgcn_mfma_f32_16x16x32_bf16(a, b, c, 0, 0, 0)
#define MFMA32(a, b, c) __builtin_amdgcn_mfma_f32_32x32x16_bf16(a, b, c, 0, 0, 0)

__device__ __forceinline__ void gload_lds16(const u16* g, u16* l) {
    __builtin_amdgcn_global_load_lds(
        (const __attribute__((address_space(1))) void*)g,
        (__attribute__((address_space(3))) void*)l, 16, 0, 0);
}

// --------------------------------------------- split + transpose weights
__global__ __launch_bounds__(256) void k_split_w(
    const float* __restrict__ wt, const float* __restrict__ wp,
    const float* __restrict__ wg, const float* __restrict__ wo,
    u16* wth, u16* wtl, u16* wph, u16* wpl, u16* wgh, u16* wgl, u16* wot) {
    int e = blockIdx.x * 256 + threadIdx.x;
    int m = blockIdx.y;
    if (m < 3) {
        const float* src = m == 0 ? wt : (m == 1 ? wp : wg);
        u16* oh = m == 0 ? wth : (m == 1 ? wph : wgh);
        u16* ol = m == 0 ? wtl : (m == 1 ? wpl : wgl);
        int r = e >> 7, c = e & 127;          // src [256][128]
        float f = src[e];
        u16 hi = f2bf(f);
        oh[c * 256 + r] = hi;
        ol[c * 256 + r] = f2bf(f - bf2f(hi));
    } else {
        int r = e >> 8, c = e & 255;          // src [128][256]
        wot[c * 128 + r] = f2bf(wo[e]);
    }
}

// --------------------- single-pass fused split + theta/phi/g projection
// 64-row blocks; x read ONCE. g keys permuted (swap bits 2<->3 of key%16)
// so attention's PV can consume P directly from S^T D-registers.
__global__ __launch_bounds__(256) void k_proj(
    const float* __restrict__ x,
    const u16* __restrict__ wth, const u16* __restrict__ wtl,
    const u16* __restrict__ wph, const u16* __restrict__ wpl,
    const u16* __restrict__ wgh,
    u16* __restrict__ th, u16* __restrict__ tl,
    u16* __restrict__ ph, u16* __restrict__ pl, u16* __restrict__ gt) {
    __shared__ u16 sxh[64][40], sxl[64][40];
    __shared__ u16 sw[5][128][40];
    int tid = threadIdx.x;
    int w = tid >> 6, lane = tid & 63, q = lane >> 4, li = lane & 15;
    int r0 = blockIdx.x * 64;
    int wr2 = (w >> 1) * 32, wcc = (w & 1) * 64;
    const u16* Ws[5] = {wth, wtl, wph, wpl, wgh};

    f32x4 aT[2][4], aP[2][4], aG[2][4];
#pragma unroll
    for (int i = 0; i < 2; i++)
#pragma unroll
        for (int j = 0; j < 4; j++) {
            aT[i][j] = (f32x4)0.f; aP[i][j] = (f32x4)0.f; aG[i][j] = (f32x4)0.f;
        }

    for (int kc = 0; kc < 8; kc++) {
        {   // stage x fp32 -> hi/lo bf16 (64 rows x 32 k)
            int row = tid >> 2, seg = tid & 3;
            const float* xp = &x[(size_t)(r0 + row) * 256 + kc * 32 + seg * 8];
            float4 v0 = ((const float4*)xp)[0];
            float4 v1 = ((const float4*)xp)[1];
            float vv[8] = {v0.x, v0.y, v0.z, v0.w, v1.x, v1.y, v1.z, v1.w};
            u16 hh[8], ll[8];
#pragma unroll
            for (int t = 0; t < 8; t++) {
                hh[t] = f2bf(vv[t]);
                ll[t] = f2bf(vv[t] - bf2f(hh[t]));
            }
            *(s16x8*)&sxh[row][seg * 8] = *(s16x8*)&hh[0];
            *(s16x8*)&sxl[row][seg * 8] = *(s16x8*)&ll[0];
        }
#pragma unroll
        for (int u = 0; u < 10; u++) {  // stage 5 weight tiles (128 cols x 32 k)
            int mat = u >> 1;
            int col = (u & 1) * 64 + (tid >> 2), ch = tid & 3;
            s16x8 v = *(const s16x8*)&Ws[mat][(size_t)col * 256 + kc * 32 + ch * 8];
            *(s16x8*)&sw[mat][col][ch * 8] = v;
        }
        __syncthreads();

        s16x8 ah[2], al[2];
#pragma unroll
        for (int i = 0; i < 2; i++) {
            ah[i] = *(const s16x8*)&sxh[wr2 + i * 16 + li][q * 8];
            al[i] = *(const s16x8*)&sxl[wr2 + i * 16 + li][q * 8];
        }
#pragma unroll
        for (int j = 0; j < 4; j++) {
            int col = wcc + j * 16 + li;
            s16x8 bth = *(const s16x8*)&sw[0][col][q * 8];
            s16x8 btl = *(const s16x8*)&sw[1][col][q * 8];
            s16x8 bph = *(const s16x8*)&sw[2][col][q * 8];
            s16x8 bpl = *(const s16x8*)&sw[3][col][q * 8];
            s16x8 bgh = *(const s16x8*)&sw[4][col][q * 8];
#pragma unroll
            for (int i = 0; i < 2; i++) {
                aT[i][j] = MFMA(ah[i], bth, aT[i][j]);
                aT[i][j] = MFMA(al[i], bth, aT[i][j]);
                aT[i][j] = MFMA(ah[i], btl, aT[i][j]);
                aP[i][j] = MFMA(ah[i], bph, aP[i][j]);
                aP[i][j] = MFMA(al[i], bph, aP[i][j]);
                aP[i][j] = MFMA(ah[i], bpl, aP[i][j]);
                aG[i][j] = MFMA(ah[i], bgh, aG[i][j]);
                aG[i][j] = MFMA(al[i], bgh, aG[i][j]);
            }
        }
        __syncthreads();
    }

#pragma unroll
    for (int i = 0; i < 2; i++)
#pragma unroll
        for (int j = 0; j < 4; j++) {
            int col = wcc + j * 16 + li;
#pragma unroll
            for (int reg = 0; reg < 4; reg++) {   // theta split
                int n = r0 + wr2 + i * 16 + q * 4 + reg;
                float v = aT[i][j][reg];
                u16 hi = f2bf(v);
                th[(size_t)n * 128 + col] = hi;
                tl[(size_t)n * 128 + col] = f2bf(v - bf2f(hi));
            }
#pragma unroll
            for (int pr = 0; pr < 2; pr++) {      // pooled phi / g
                int n = r0 + wr2 + i * 16 + q * 4 + pr * 2;
                int mrow = n >> 1;
                float vp = fmaxf(aP[i][j][pr * 2], aP[i][j][pr * 2 + 1]);
                u16 hi = f2bf(vp);
                ph[(size_t)mrow * 128 + col] = hi;
                pl[(size_t)mrow * 128 + col] = f2bf(vp - bf2f(hi));
                float vg = fmaxf(aG[i][j][pr * 2], aG[i][j][pr * 2 + 1]);
                int b = n >> 12;
                int mi = mrow & 2047;
                int mi2 = (mi & ~12) | ((mi & 4) << 1) | ((mi & 8) >> 1);  // PV perm
                gt[(size_t)b * (128 * 2048) + (size_t)col * 2048 + mi2] = f2bf(vg);
            }
        }
}

// ------------------------------------------------------- flash attention
// 32 q/wave, split-K x2. P consumed directly from S^T D-regs (g keys
// pre-permuted in k_proj). LDS 48 KB, launch_bounds(256,2): no spills.
__global__ __launch_bounds__(256, 2) void k_attn(
    const u16* __restrict__ th, const u16* __restrict__ tl,
    const u16* __restrict__ ph, const u16* __restrict__ pl,
    const u16* __restrict__ gt, u16* __restrict__ ot,
    float* __restrict__ Mv, float* __restrict__ Lv) {
    __shared__ u16 smem[24576];          // 48 KB
    u16* skh = smem;                     // 64 x 128, chunk16 ^= row&7
    u16* skl = smem + 8192;
    u16* sg  = smem + 16384;             // 128 x 64, chunk16 ^= row&7
    int tid = threadIdx.x, w = tid >> 6, lane = tid & 63;
    int q = lane & 31, b = lane >> 5;
    int bb = blockIdx.y;
    int s = blockIdx.x & 1;
    int qt = blockIdx.x >> 1;
    int n0 = qt * 128;
    int row128 = w * 32 + q;
    size_t qrow = ((size_t)bb * 4096 + n0 + row128) * 128;

    s16x8 Qh[8], Ql[8];
#pragma unroll
    for (int ks = 0; ks < 8; ks++) {
        Qh[ks] = *(const s16x8*)&th[qrow + ks * 16 + b * 8];
        Ql[ks] = *(const s16x8*)&tl[qrow + ks * 16 + b * 8];
    }
    float mrow = -INFINITY, lrow = 0.f;
    f32x16 o[4];
#pragma unroll
    for (int c = 0; c < 4; c++) o[c] = (f32x16)0.f;

    int r_hi = lane >> 4, c_hi = lane & 15;
    int r_lo = lane >> 3, c_lo = lane & 7;
    int k0 = s * 1024;

    for (int kt = 0; kt < 16; kt++) {
        int m0 = k0 + kt * 64;
        if (kt) __syncthreads();
#pragma unroll
        for (int jj = 0; jj < 4; jj++) {
            int r = w * 16 + jj * 4 + r_hi;
            int gc = c_hi ^ (r & 7);
            size_t ga = (((size_t)(bb * 2048 + m0 + r)) << 7) + gc * 8;
            gload_lds16(&ph[ga], &skh[(w * 16 + jj * 4) << 7]);
            gload_lds16(&pl[ga], &skl[(w * 16 + jj * 4) << 7]);
            int r2 = w * 32 + jj * 8 + r_lo;
            int gc2 = c_lo ^ (r2 & 7);
            size_t ga2 = (size_t)bb * (128 * 2048) + (size_t)r2 * 2048 + m0 + gc2 * 8;
            gload_lds16(&gt[ga2], &sg[(w * 32 + jj * 8) << 6]);
        }
        __syncthreads();

        // S^T = phi . theta^T : D[key][query], col = query = lane&31
        f32x16 S[2];
        S[0] = (f32x16)0.f; S[1] = (f32x16)0.f;
#pragma unroll
        for (int ks = 0; ks < 8; ks++) {
            int off0 = (q << 7) + (((ks * 2 + b) ^ (q & 7)) << 3);
            int r1 = 32 + q;
            int off1 = (r1 << 7) + (((ks * 2 + b) ^ (r1 & 7)) << 3);
            s16x8 ah0 = *(const s16x8*)&skh[off0];
            s16x8 al0 = *(const s16x8*)&skl[off0];
            s16x8 ah1 = *(const s16x8*)&skh[off1];
            s16x8 al1 = *(const s16x8*)&skl[off1];
            S[0] = MFMA32(ah0, Qh[ks], S[0]);
            S[1] = MFMA32(ah1, Qh[ks], S[1]);
            S[0] = MFMA32(al0, Qh[ks], S[0]);
            S[1] = MFMA32(al1, Qh[ks], S[1]);
            S[0] = MFMA32(ah0, Ql[ks], S[0]);
            S[1] = MFMA32(ah1, Ql[ks], S[1]);
        }

        // online softmax: per-thread over 32 keys + one xor-32 shuffle
        float vmax = S[0][0];
#pragma unroll
        for (int r = 0; r < 16; r++) {
            vmax = fmaxf(vmax, S[0][r]);
            vmax = fmaxf(vmax, S[1][r]);
        }
        vmax = fmaxf(vmax, __shfl_xor(vmax, 32, 64));
        float nm = fmaxf(mrow, vmax);
        float alph = __expf(mrow - nm);
        mrow = nm;
        float rs = 0.f;
#pragma unroll
        for (int r = 0; r < 16; r++) {
            float p0 = __expf(S[0][r] - nm); S[0][r] = p0; rs += p0;
            float p1 = __expf(S[1][r] - nm); S[1][r] = p1; rs += p1;
        }
        rs += __shfl_xor(rs, 32, 64);
        lrow = lrow * alph + rs;
#pragma unroll
        for (int c = 0; c < 4; c++)
#pragma unroll
            for (int r = 0; r < 16; r++) o[c][r] *= alph;

        // P @ V: B-fragments packed straight from S D-regs (no LDS!)
#pragma unroll
        for (int t = 0; t < 4; t++) {
            int half = t >> 1, base = (t & 1) * 8;
            s16x8 Pf;
            u32* pf = (u32*)&Pf;
#pragma unroll
            for (int r2 = 0; r2 < 4; r2++)
                pf[r2] = pkbf(S[half][base + 2 * r2], S[half][base + 2 * r2 + 1]);
#pragma unroll
            for (int c = 0; c < 4; c++) {
                int ch = c * 32 + q;
                int off = (ch << 6) + (((t * 2 + b) ^ (ch & 7)) << 3);
                s16x8 gv = *(const s16x8*)&sg[off];
                o[c] = MFMA32(gv, Pf, o[c]);
            }
        }
    }
    __syncthreads();

    // epilogue: LDS transpose O^T[ch][q] -> [q][ch], store bf16 unnormalized
    u16* sc = smem;  // 128 x 136 u16 = 34816 B
#pragma unroll
    for (int c = 0; c < 4; c++)
#pragma unroll
        for (int r2 = 0; r2 < 8; r2++) {
            int ch = c * 32 + ((r2 & 1) << 1) + 8 * (r2 >> 1) + 4 * b;
            u32 pk = (u32)f2bf(o[c][2 * r2]) | ((u32)f2bf(o[c][2 * r2 + 1]) << 16);
            *(u32*)&sc[row128 * 136 + ch] = pk;
        }
    __syncthreads();
    size_t obase = ((size_t)s * 32768 + (size_t)bb * 4096 + n0) * 128;
    int rowy = tid >> 1;
#pragma unroll
    for (int j = 0; j < 8; j++) {
        int chk = (tid & 1) * 8 + j;
        s16x8 v = *(const s16x8*)&sc[rowy * 136 + chk * 8];
        *(s16x8*)&ot[obase + (size_t)rowy * 128 + chk * 8] = v;
    }
    if (b == 0) {
        int gi = s * 32768 + bb * 4096 + n0 + row128;
        Mv[gi] = mrow;
        Lv[gi] = lrow;
    }
}

// ------------- output GEMM + residual + split-K combine, float4 epilogue
__global__ __launch_bounds__(256) void k_out(
    const u16* __restrict__ ot, const float* __restrict__ Mv,
    const float* __restrict__ Lv, const u16* __restrict__ wot,
    const float* __restrict__ x, float* __restrict__ out) {
    __shared__ char lds_o[36864];
    u16 (*sy)[72] = (u16(*)[72])lds_o;
    u16 (*sw)[72] = (u16(*)[72])(lds_o + 18432);
    int tid = threadIdx.x, w = tid >> 6, lane = tid & 63, q = lane >> 4, li = lane & 15;
    int r0 = blockIdx.x * 128, c0 = blockIdx.y * 128;
    int wr = (w >> 1) * 64, wc = (w & 1) * 64;
    const size_t OS = (size_t)32768 * 128;

    float a1v[4], a2v[4];
#pragma unroll
    for (int i = 0; i < 4; i++) {
        int gr = r0 + ((tid + i * 256) >> 3);
        float m1 = Mv[gr], m2 = Mv[32768 + gr];
        float l1 = Lv[gr], l2 = Lv[32768 + gr];
        float Mx = fmaxf(m1, m2);
        float e1 = __expf(m1 - Mx), e2 = __expf(m2 - Mx);
        float inv = 1.f / (l1 * e1 + l2 * e2);
        a1v[i] = e1 * inv;
        a2v[i] = e2 * inv;
    }

    f32x4 acc[4][4];
#pragma unroll
    for (int i = 0; i < 4; i++)
#pragma unroll
        for (int j = 0; j < 4; j++) acc[i][j] = (f32x4)0.f;

    for (int kc = 0; kc < 2; kc++) {
#pragma unroll
        for (int i = 0; i < 4; i++) {
            int ch = tid + i * 256;
            int r = ch >> 3, cc = (ch & 7) * 8;
            size_t ga = (size_t)(r0 + r) * 128 + kc * 64 + cc;
            s16x8 o1 = *(const s16x8*)&ot[ga];
            s16x8 o2 = *(const s16x8*)&ot[OS + ga];
            s16x8 yv;
#pragma unroll
            for (int e = 0; e < 8; e++)
                yv[e] = (short)f2bf(bf2f((u16)o1[e]) * a1v[i] +
                                    bf2f((u16)o2[e]) * a2v[i]);
            *(s16x8*)&sy[r][cc] = yv;
            *(s16x8*)&sw[r][cc] = *(const s16x8*)&wot[(size_t)(c0 + r) * 128 + kc * 64 + cc];
        }
        __syncthreads();
#pragma unroll
        for (int ks = 0; ks < 2; ks++)
#pragma unroll
            for (int i = 0; i < 4; i++) {
                s16x8 a = *(const s16x8*)&sy[wr + i * 16 + li][ks * 32 + q * 8];
#pragma unroll
                for (int j = 0; j < 4; j++) {
                    s16x8 bv = *(const s16x8*)&sw[wc + j * 16 + li][ks * 32 + q * 8];
                    acc[i][j] = MFMA(a, bv, acc[i][j]);
                }
            }
        __syncthreads();
    }

    // float4 epilogue via LDS transpose, 2 chunks of 64 rows
    float* sT = (float*)lds_o;           // 64 x 132 f32 = 33792 B
#pragma unroll
    for (int h = 0; h < 2; h++) {
        __syncthreads();
        if ((w >> 1) == h) {
#pragma unroll
            for (int i = 0; i < 4; i++)
#pragma unroll
                for (int j = 0; j < 4; j++)
#pragma unroll
                    for (int reg = 0; reg < 4; reg++)
                        sT[(i * 16 + q * 4 + reg) * 132 + wc + j * 16 + li] =
                            acc[i][j][reg];
        }
        __syncthreads();
#pragma unroll
        for (int p = 0; p < 8; p++) {
            int r = (tid >> 5) + p * 8;
            int c4 = (tid & 31) * 4;
            f32x4 yv = *(f32x4*)&sT[r * 132 + c4];
            size_t row = (size_t)(r0 + h * 64 + r);
            float4 xv = *(const float4*)&x[row * 256 + c0 + c4];
            float4 ov;
            ov.x = xv.x + yv[0]; ov.y = xv.y + yv[1];
            ov.z = xv.z + yv[2]; ov.w = xv.w + yv[3];
            *(float4*)&out[row * 256 + c0 + c4] = ov;
        }
    }
}

// ---------------------------------------------------------------- launch
extern "C" void kernel_launch(void* const* d_in, const int* in_sizes, int n_in,
                              void* d_out, int out_size, void* d_ws, size_t ws_size,
                              hipStream_t stream) {
    const float* x  = (const float*)d_in[0];
    const float* wt = (const float*)d_in[1];
    const float* wp = (const float*)d_in[2];
    const float* wg = (const float*)d_in[3];
    const float* wo = (const float*)d_in[4];
    float* out = (float*)d_out;

    char* p = (char*)d_ws;
    auto alloc = [&](size_t bytes) {
        char* r = p;
        p += (bytes + 255) & ~(size_t)255;
        return r;
    };
    const size_t NT = (size_t)BB * NN * CBD;   // 4194304
    const size_t NP = (size_t)BB * MM * CBD;   // 2097152

    u16* wth = (u16*)alloc(CC * CBD * 2);
    u16* wtl = (u16*)alloc(CC * CBD * 2);
    u16* wph = (u16*)alloc(CC * CBD * 2);
    u16* wpl = (u16*)alloc(CC * CBD * 2);
    u16* wgh = (u16*)alloc(CC * CBD * 2);
    u16* wgl = (u16*)alloc(CC * CBD * 2);
    u16* wot = (u16*)alloc(CC * CBD * 2);
    u16* th  = (u16*)alloc(NT * 2);
    u16* tl  = (u16*)alloc(NT * 2);
    u16* ph  = (u16*)alloc(NP * 2);
    u16* pl  = (u16*)alloc(NP * 2);
    u16* gt  = (u16*)alloc(NP * 2);
    float* Mv = (float*)alloc(2 * 32768 * 4);
    float* Lv = (float*)alloc(2 * 32768 * 4);
    u16* ot  = (u16*)alloc(2 * NT * 2);        // [2][32768][128] bf16

    k_split_w<<<dim3(128, 4), 256, 0, stream>>>(wt, wp, wg, wo,
                                                wth, wtl, wph, wpl, wgh, wgl, wot);
    k_proj<<<dim3(512), 256, 0, stream>>>(x, wth, wtl, wph, wpl, wgh,
                                          th, tl, ph, pl, gt);
    k_attn<<<dim3(64, 8), 256, 0, stream>>>(th, tl, ph, pl, gt, ot, Mv, Lv);
    k_out<<<dim3(256, 2), 256, 0, stream>>>(ot, Mv, Lv, wot, x, out);
}